// Round 10
// baseline (220.354 us; speedup 1.0000x reference)
//
#include <hip/hip_runtime.h>
#include <hip/hip_bf16.h>

// SelfAttention: x[8,256,48,48] fp32; wq/wk/wv[256,256] fp32.
// out = x + attn(softmax(q^T k), v). B=8, C=256, N=2304. fp16 MFMA path.
//
// R9 post-mortem: reg-capped 2 waves/SIMD + per-iter vmcnt(0) drain at
// __syncthreads left LDS pipe at 45% util. R10: (1) V register-streamed from
// global (frag-order loads are coalesced, L2-resident) -> LDS traffic -40%;
// (2) K triple-buffered (3x16KB), staged 2-ahead, raw s_barrier, no vmcnt(0)
// in loop: V loads issued after prev K-stage make the compiler's V-wait
// imply K(t+1) landed (in-order vmcnt); (3) qkv_proj z-merged (x read once).
//
// K_swz[kb][ks 16][hi 2][key 32][j 8]: short off = kb*8192+ks*512+hi*256+key*8+j
//   holds K[key of chunk kb][c = 16ks+8hi+j]   (A-frag for QK^T)
// V_swz[kb][ct 8][kh 2][hi 2][c 32][j 8]: off = kb*8192+ct*1024+kh*512+hi*256+c*8+j
//   holds V[c = 32ct+cloc][key = 16kh+8hi+j]   (A-frag = V^T for PV)
// ws: wq/wk/wv fp16 [65536 ea]; Qt [B*N*C] token-major; Ksw,Vsw [B*N*C];
//     P fp16 [splits][B][C][N] (per-split normalized O_s); ml f32 [splits][B][N][2].

#define DEVI __device__ __forceinline__

typedef _Float16 f16x8 __attribute__((ext_vector_type(8)));
typedef float f32x4 __attribute__((ext_vector_type(4)));
typedef float f32x16 __attribute__((ext_vector_type(16)));

constexpr int Bn = 8, Cn = 256, Nn = 48 * 48;   // 2304

DEVI unsigned short f2h(float f) {
  _Float16 h = (_Float16)f;
  return __builtin_bit_cast(unsigned short, h);
}
DEVI float h2f(unsigned short u) {
  return (float)__builtin_bit_cast(_Float16, u);
}
DEVI unsigned pk2(float a, float b) {           // pack 2 f32 -> f16x2 (RTZ)
  auto h = __builtin_amdgcn_cvt_pkrtz(a, b);
  return __builtin_bit_cast(unsigned, h);
}
DEVI void stage16(const unsigned short* g, unsigned short* l) {
  __builtin_amdgcn_global_load_lds(
      (const __attribute__((address_space(1))) void*)g,
      (__attribute__((address_space(3))) void*)l, 16, 0, 0);
}

#define MFMA16(a, b, c) __builtin_amdgcn_mfma_f32_16x16x32_f16((a), (b), (c), 0, 0, 0)
#define MFMA32(a, b, c) __builtin_amdgcn_mfma_f32_32x32x16_f16((a), (b), (c), 0, 0, 0)

__global__ __launch_bounds__(256) void cvt_w(const float* __restrict__ wq,
                                             const float* __restrict__ wk,
                                             const float* __restrict__ wv,
                                             unsigned short* __restrict__ o) {
  int idx = blockIdx.x * 256 + threadIdx.x;     // 3*65536 total
  const float* s = (idx < Cn * Cn) ? wq : (idx < 2 * Cn * Cn) ? wk : wv;
  o[idx] = f2h(s[idx & (Cn * Cn - 1)]);
}

// ---------------- QKV projection (z-merged: x staged once) ----------------
// grid (N/64, B), 256 thr (4 waves, 16 tokens each).
// 16x16x32 frags: A/B lane l: row/col=l&15, k=8*(l>>4)+j. C/D: col=l&15, row=4*(l>>4)+r.
__global__ __launch_bounds__(256) void qkv_proj(
    const float* __restrict__ x,
    const unsigned short* __restrict__ wqb, const unsigned short* __restrict__ wkb,
    const unsigned short* __restrict__ wvb,
    unsigned short* __restrict__ Qt, unsigned short* __restrict__ Ksw,
    unsigned short* __restrict__ Vsw) {
  __shared__ unsigned short xT[64][264];        // [token][c], +8 pad
  const int tid = threadIdx.x;
  const int n0 = blockIdx.x * 64;
  const int b = blockIdx.y;
  const float* xb = x + (size_t)b * Cn * Nn;
  {
    int cbase = tid >> 4;
    int nn = (tid & 15) * 4;
#pragma unroll
    for (int it = 0; it < 16; ++it) {
      int c = cbase + 16 * it;
      float4 v = *(const float4*)(xb + (size_t)c * Nn + n0 + nn);
      xT[nn + 0][c] = f2h(v.x);
      xT[nn + 1][c] = f2h(v.y);
      xT[nn + 2][c] = f2h(v.z);
      xT[nn + 3][c] = f2h(v.w);
    }
  }
  __syncthreads();
  const int lane = tid & 63, w = tid >> 6;
  const int i = lane & 15, g = lane >> 4;
  f16x8 xf[8];                                  // x^T frags
#pragma unroll
  for (int ks = 0; ks < 8; ++ks)
    xf[ks] = *(const f16x8*)(&xT[w * 16 + i][32 * ks + 8 * g]);

  const int kb0 = (n0 >> 5) + (w >> 1);         // 32-token chunk id
  {                                             // Q -> token-major [N][C]
    const size_t tokbase = (size_t)b * Nn + n0 + w * 16;
    for (int ot = 0; ot < 16; ++ot) {
      f32x4 acc = {0.f, 0.f, 0.f, 0.f};
      const unsigned short* wr = wqb + (ot * 16 + i) * Cn + 8 * g;
#pragma unroll
      for (int ks = 0; ks < 8; ++ks)
        acc = MFMA16(xf[ks], *(const f16x8*)(wr + 32 * ks), acc);
#pragma unroll
      for (int r = 0; r < 4; ++r)
        Qt[(tokbase + 4 * g + r) * Cn + ot * 16 + i] = f2h(acc[r]);
    }
  }
  {                                             // K -> frag-swizzled
    // acc[r] = K[tok = n0+w16+4g+r][c = ot*16+i]
    unsigned short* kout = Ksw + (size_t)b * Nn * Cn + (size_t)kb0 * 8192
                         + ((i >> 3) & 1) * 256 + (i & 7);
    const int keyb = (w & 1) * 16 + 4 * g;      // + r
    for (int ot = 0; ot < 16; ++ot) {
      f32x4 acc = {0.f, 0.f, 0.f, 0.f};
      const unsigned short* wr = wkb + (ot * 16 + i) * Cn + 8 * g;
#pragma unroll
      for (int ks = 0; ks < 8; ++ks)
        acc = MFMA16(xf[ks], *(const f16x8*)(wr + 32 * ks), acc);
#pragma unroll
      for (int r = 0; r < 4; ++r)
        kout[ot * 512 + (keyb + r) * 8] = f2h(acc[r]);
    }
  }
  {                                             // V -> frag-swizzled (V^T A-frags)
    // acc[r] = V[c = ot*16+4g+r][tok = n0+w16+i]
    unsigned short* vout = Vsw + (size_t)b * Nn * Cn + (size_t)kb0 * 8192
                         + (w & 1) * 512 + ((i >> 3) & 1) * 256 + (i & 7);
    for (int ot = 0; ot < 16; ++ot) {
      f32x4 acc = {0.f, 0.f, 0.f, 0.f};
      const unsigned short* wr = wvb + (ot * 16 + i) * Cn + 8 * g;
#pragma unroll
      for (int ks = 0; ks < 8; ++ks)
        acc = MFMA16(*(const f16x8*)(wr + 32 * ks), xf[ks], acc);
#pragma unroll
      for (int r = 0; r < 4; ++r) {
        int c = ot * 16 + 4 * g + r;
        vout[(c >> 5) * 1024 + (c & 31) * 8] = f2h(acc[r]);
      }
    }
  }
}

// ---- flash attention: split-K, K triple-buffered LDS, V reg-streamed ------
// grid Bn*splits*36, 256 thr = 4 waves = 2 q-tiles(32q) x 2 c-halves(128c).
// LDS 48KB = 3 x 16KB K bufs. Raw s_barrier per iter; K staged 2-ahead;
// V global loads issued first each iter (their compiler vmcnt wait implies
// prev K-stage landed; in-order vmcnt). No vmcnt(0) in loop.
__global__ __launch_bounds__(256, 2) void attn_split(
    const unsigned short* __restrict__ Qt, const unsigned short* __restrict__ Ksw,
    const unsigned short* __restrict__ Vsw,
    unsigned short* __restrict__ P, float* __restrict__ ml, int splits) {
  __shared__ unsigned short smem[24576];        // 48 KB
  const int nblk = gridDim.x;                   // divisible by 8
  const int cpx = nblk >> 3;
  const int swz = (blockIdx.x & 7) * cpx + (blockIdx.x >> 3);  // XCD chunked
  const int per_b = splits * 36;
  const int b = swz / per_b;
  const int rem = swz - b * per_b;
  const int s = rem / 36;
  const int qt = rem - s * 36;
  const int n0 = qt * 64;
  const int kn = Nn / splits;
  const int kb0 = (s * kn) >> 5;                // first 32-key chunk id
  const int NT = kn / 32;                       // >= 18

  const int tid = threadIdx.x, lane = tid & 63, w = tid >> 6;
  const int q = lane & 31, hi = lane >> 5;
  const int qtile = w & 1, chalf = w >> 1;
  const int q0 = n0 + qtile * 32;

  const unsigned short* Ksrc = Ksw + (size_t)b * Nn * Cn + tid * 8;
  const unsigned short* Vb = Vsw + (size_t)b * Nn * Cn + hi * 256 + q * 8
                           + (size_t)chalf * 4096;

  auto stageK = [&](int kbid, int buf) {        // linear 16KB chunk copy
    unsigned short* dst = smem + buf * 8192 + w * 512;
    const unsigned short* src = Ksrc + (size_t)kbid * 8192;
#pragma unroll
    for (int c4 = 0; c4 < 4; ++c4)
      stage16(src + c4 * 2048, dst + c4 * 2048);
  };

  // resident Q B-frags: lane: query=q, c = 16*ks + 8*hi + j
  const unsigned short* Qb = Qt + ((size_t)b * Nn + q0 + q) * Cn + 8 * hi;
  f16x8 qf[16];
#pragma unroll
  for (int ks = 0; ks < 16; ++ks) qf[ks] = *(const f16x8*)(Qb + 16 * ks);

  stageK(kb0, 0);                               // prologue: 2-ahead
  stageK(kb0 + 1, 1);

  f32x16 acc[4];                                // channels chalf*128 .. +128
#pragma unroll
  for (int ct = 0; ct < 4; ++ct) acc[ct] = (f32x16)(0.f);
  float m = -1e30f, lsum = 0.f;

  asm volatile("s_waitcnt vmcnt(4)" ::: "memory");   // own K0 landed (K1 in flight)
  __builtin_amdgcn_sched_barrier(0);
  __builtin_amdgcn_s_barrier();                 // all waves' K0 landed

  for (int t = 0; t < NT; ++t) {
    // ---- V frags for this iter: coalesced global, consumed at PV ----
    f16x8 vf[8];
    {
      const unsigned short* vp = Vb + (size_t)(kb0 + t) * 8192;
#pragma unroll
      for (int ct = 0; ct < 4; ++ct) {
        vf[2 * ct] = *(const f16x8*)(vp + ct * 1024);
        vf[2 * ct + 1] = *(const f16x8*)(vp + ct * 1024 + 512);
      }
    }
    __builtin_amdgcn_sched_barrier(0);          // keep V issues before K stage
    if (t + 2 < NT) stageK(kb0 + t + 2, (t + 2) % 3);

    const char* KsB = (const char*)smem + (t % 3) * 16384;
    const int lo = hi * 512 + q * 16;           // byte offset within frag row

    // ---- QK^T: d[key][query], 2 independent 8-MFMA chains over c=256 ----
    f32x16 da = (f32x16)(0.f), db = (f32x16)(0.f);
#pragma unroll
    for (int ks = 0; ks < 8; ++ks) {
      da = MFMA32(*(const f16x8*)(KsB + ks * 1024 + lo), qf[ks], da);
      db = MFMA32(*(const f16x8*)(KsB + (ks + 8) * 1024 + lo), qf[ks + 8], db);
    }
    f32x16 d = da + db;

    // ---- online softmax: lane owns query q, 16 scores ----
    float mx = d[0];
#pragma unroll
    for (int r = 1; r < 16; ++r) mx = fmaxf(mx, d[r]);
    mx = fmaxf(mx, __shfl_xor(mx, 32));         // full 32-key max
    if (__any(mx > m + 8.f)) {                  // defer-max (THR=8)
      float mnew = fmaxf(m, mx);
      float alpha = __expf(m - mnew);
      m = mnew;
      lsum *= alpha;
#pragma unroll
      for (int ct = 0; ct < 4; ++ct)
#pragma unroll
        for (int r = 0; r < 16; ++r) acc[ct][r] *= alpha;
    }
    float p[16];
#pragma unroll
    for (int r = 0; r < 16; ++r) p[r] = __expf(d[r] - m);
    float cs = 0.f;
#pragma unroll
    for (int r = 0; r < 16; ++r) cs += p[r];
    cs += __shfl_xor(cs, 32);
    lsum += cs;

    // ---- P -> B-frags (keys 0..15 | 16..31), half-wave exchange ----
    unsigned A0 = pk2(p[0], p[1]), A1 = pk2(p[2], p[3]);
    unsigned A2 = pk2(p[4], p[5]), A3 = pk2(p[6], p[7]);
    unsigned A4 = pk2(p[8], p[9]), A5 = pk2(p[10], p[11]);
    unsigned A6 = pk2(p[12], p[13]), A7 = pk2(p[14], p[15]);
    unsigned s0 = __shfl_xor(A0, 32), s1 = __shfl_xor(A1, 32);
    unsigned s2 = __shfl_xor(A2, 32), s3 = __shfl_xor(A3, 32);
    unsigned s4 = __shfl_xor(A4, 32), s5 = __shfl_xor(A5, 32);
    unsigned s6 = __shfl_xor(A6, 32), s7 = __shfl_xor(A7, 32);
    union { unsigned u[4]; f16x8 v; } pb0, pb1;
    pb0.u[0] = hi ? s2 : A0;  pb0.u[1] = hi ? s3 : A1;
    pb0.u[2] = hi ? A2 : s0;  pb0.u[3] = hi ? A3 : s1;
    pb1.u[0] = hi ? s6 : A4;  pb1.u[1] = hi ? s7 : A5;
    pb1.u[2] = hi ? A6 : s4;  pb1.u[3] = hi ? A7 : s5;

    // ---- PV: 4 c-tiles of this wave's c-half, V from registers ----
#pragma unroll
    for (int ct = 0; ct < 4; ++ct) {
      acc[ct] = MFMA32(vf[2 * ct], pb0.v, acc[ct]);
      acc[ct] = MFMA32(vf[2 * ct + 1], pb1.v, acc[ct]);
    }
    __builtin_amdgcn_sched_barrier(0);
    __builtin_amdgcn_s_barrier();               // raw: no vmcnt(0) drain
  }

  // ---- epilogue: O_s = acc/lsum -> fp16; c = 32ctg + (r&3)+8*(r>>2)+4hi ----
  const float rl = 1.f / lsum;
  unsigned short* Pb = P + (size_t)(s * Bn + b) * Cn * Nn;
#pragma unroll
  for (int ct = 0; ct < 4; ++ct)
#pragma unroll
    for (int r = 0; r < 16; ++r) {
      int c = 32 * (chalf * 4 + ct) + (r & 3) + 8 * (r >> 2) + 4 * hi;
      Pb[(size_t)c * Nn + q0 + q] = f2h(acc[ct][r] * rl);
    }
  if (!hi && !chalf)
    *(float2*)&ml[((size_t)(s * Bn + b) * Nn + q0 + q) * 2] = make_float2(m, lsum);
}

// ---------------- combine partials + residual ----------------
// out = x + sum_s w_s * O_s,  w_s = exp(m_s - M) * l_s / sum(exp(m_s-M) l_s).
__global__ __launch_bounds__(256) void combine_k(
    const float* __restrict__ x, const unsigned short* __restrict__ P,
    const float* __restrict__ ml, float* __restrict__ out, int splits) {
  __shared__ float sc[4][32];
  const int tpb = Nn / 32;                      // 72
  const int b = blockIdx.x / tpb;
  const int n0 = (blockIdx.x - b * tpb) * 32;
  const int t = threadIdx.x;
  if (t < 32) {
    const int n = n0 + t;
    const size_t sstr = (size_t)Bn * Nn * 2;
    const float* mlb = ml + ((size_t)b * Nn + n) * 2;
    float m0 = mlb[0], l0 = mlb[1];
    float m1 = -1e30f, l1 = 0.f, m2 = -1e30f, l2 = 0.f, m3 = -1e30f, l3 = 0.f;
    if (splits > 1) { m1 = mlb[sstr]; l1 = mlb[sstr + 1]; }
    if (splits > 2) { m2 = mlb[2 * sstr]; l2 = mlb[2 * sstr + 1]; }
    if (splits > 3) { m3 = mlb[3 * sstr]; l3 = mlb[3 * sstr + 1]; }
    float M = fmaxf(fmaxf(m0, m1), fmaxf(m2, m3));
    float g0 = __expf(m0 - M) * l0, g1 = __expf(m1 - M) * l1;
    float g2 = __expf(m2 - M) * l2, g3 = __expf(m3 - M) * l3;
    float rden = 1.f / (g0 + g1 + g2 + g3);
    sc[0][t] = g0 * rden; sc[1][t] = g1 * rden;
    sc[2][t] = g2 * rden; sc[3][t] = g3 * rden;
  }
  __syncthreads();
  const int nl4 = (t & 7) * 4, c0 = t >> 3;
  const size_t pstr = (size_t)Bn * Cn * Nn;     // shorts per split
  const float* xb = x + (size_t)b * Cn * Nn;
  float* ob = out + (size_t)b * Cn * Nn;
#pragma unroll
  for (int k = 0; k < 8; ++k) {
    const int c = c0 + 32 * k;
    const unsigned short* Pp = P + ((size_t)b * Cn + c) * Nn + n0 + nl4;
    f32x4 a = {0.f, 0.f, 0.f, 0.f};
    for (int s2 = 0; s2 < splits; ++s2) {
      ushort4 ph = *(const ushort4*)(Pp + s2 * pstr);
      f32x4 pv = {h2f(ph.x), h2f(ph.y), h2f(ph.z), h2f(ph.w)};
      f32x4 sw = {sc[s2][nl4 + 0], sc[s2][nl4 + 1], sc[s2][nl4 + 2], sc[s2][nl4 + 3]};
      a += sw * pv;
    }
    f32x4 xv = *(const f32x4*)(xb + (size_t)c * Nn + n0 + nl4);
    *(f32x4*)(ob + (size_t)c * Nn + n0 + nl4) = xv + a;
  }
}

extern "C" void kernel_launch(void* const* d_in, const int* in_sizes, int n_in,
                              void* d_out, int out_size, void* d_ws, size_t ws_size,
                              hipStream_t stream) {
  const float* x = (const float*)d_in[0];
  const float* wq = (const float*)d_in[1];
  const float* wk = (const float*)d_in[2];
  const float* wv = (const float*)d_in[3];
  float* out = (float*)d_out;

  unsigned short* wqb = (unsigned short*)d_ws;
  unsigned short* wkb = wqb + Cn * Cn;
  unsigned short* wvb = wkb + Cn * Cn;
  unsigned short* Qt = wvb + Cn * Cn;
  unsigned short* Ksw = Qt + (size_t)Bn * Nn * Cn;
  unsigned short* Vsw = Ksw + (size_t)Bn * Nn * Cn;
  unsigned short* P = Vsw + (size_t)Bn * Nn * Cn;

  const size_t baseB = (size_t)(3 * Cn * Cn + 3 * (size_t)Bn * Nn * Cn) * 2;
  const size_t perSplitB = (size_t)Bn * Nn * Cn * 2 + (size_t)Bn * Nn * 2 * 4;

  int splits = 1;
  if (baseB + 4 * perSplitB <= ws_size) splits = 4;
  else if (baseB + 2 * perSplitB <= ws_size) splits = 2;

  float* ml = (float*)(P + (size_t)splits * Bn * Nn * Cn);

  hipLaunchKernelGGL(cvt_w, dim3(3 * Cn * Cn / 256), dim3(256), 0, stream, wq, wk, wv, wqb);
  hipLaunchKernelGGL(qkv_proj, dim3(Nn / 64, Bn), dim3(256), 0, stream,
                     x, wqb, wkb, wvb, Qt, Ksw, Vsw);
  hipLaunchKernelGGL(attn_split, dim3(Bn * splits * 36), dim3(256), 0, stream,
                     Qt, Ksw, Vsw, P, ml, splits);
  hipLaunchKernelGGL(combine_k, dim3(Bn * Nn / 32), dim3(256), 0, stream,
                     x, P, ml, out, splits);
}